// Round 7
// baseline (906.684 us; speedup 1.0000x reference)
//
#include <hip/hip_runtime.h>
#include <math.h>

#define HDIM 768
#define DD 64
#define SEQL 1024
#define NH 12
#define NB 8

typedef float f32x4 __attribute__((ext_vector_type(4)));

// ---------------- Kernel 1: seq = hidden@W1+b1, RoPE(q,k), bias = seq@W2+b2 ----------------
// 512 blocks x 128 threads; each block does 16 rows of the 8192-row problem. (unchanged)
__global__ __launch_bounds__(128) void k1_seq_rope_bias(
    const float* __restrict__ hidden, const float* __restrict__ W1,
    const float* __restrict__ b1, const float* __restrict__ W2,
    const float* __restrict__ b2,
    float* __restrict__ qo, float* __restrict__ ko,
    float* __restrict__ bqo, float* __restrict__ bko)
{
    __shared__ float hs[16 * HDIM];   // 48 KB: 16 hidden rows
    __shared__ float sq[16][132];     // seq tile (pad 132 for banks)
    const int tid = threadIdx.x;
    const long row0 = (long)blockIdx.x * 16;

    const float4* src = (const float4*)(hidden + row0 * HDIM);
    float4* hdst = (float4*)hs;
    #pragma unroll
    for (int t = 0; t < 24; ++t)
        hdst[tid + t * 128] = src[tid + t * 128];
    __syncthreads();

    const int cx = tid & 31;
    const int ry = tid >> 5;
    const float4 bias1 = ((const float4*)b1)[cx];
    float4 acc[4];
    #pragma unroll
    for (int r = 0; r < 4; ++r) acc[r] = bias1;

    for (int k4 = 0; k4 < HDIM / 4; ++k4) {
        float4 w[4];
        #pragma unroll
        for (int kk = 0; kk < 4; ++kk)
            w[kk] = *(const float4*)(W1 + (k4 * 4 + kk) * 128 + cx * 4);
        #pragma unroll
        for (int r = 0; r < 4; ++r) {
            float4 hv = *(const float4*)(hs + (ry * 4 + r) * HDIM + k4 * 4);
            acc[r].x = fmaf(hv.x, w[0].x, fmaf(hv.y, w[1].x, fmaf(hv.z, w[2].x, fmaf(hv.w, w[3].x, acc[r].x))));
            acc[r].y = fmaf(hv.x, w[0].y, fmaf(hv.y, w[1].y, fmaf(hv.z, w[2].y, fmaf(hv.w, w[3].y, acc[r].y))));
            acc[r].z = fmaf(hv.x, w[0].z, fmaf(hv.y, w[1].z, fmaf(hv.z, w[2].z, fmaf(hv.w, w[3].z, acc[r].z))));
            acc[r].w = fmaf(hv.x, w[0].w, fmaf(hv.y, w[1].w, fmaf(hv.z, w[2].w, fmaf(hv.w, w[3].w, acc[r].w))));
        }
    }
    #pragma unroll
    for (int r = 0; r < 4; ++r)
        *(float4*)&sq[ry * 4 + r][cx * 4] = acc[r];
    __syncthreads();

    for (int idx = tid; idx < 16 * 24; idx += 128) {
        int r = idx / 24, jj = idx - r * 24;
        float s = b2[jj];
        #pragma unroll 16
        for (int c = 0; c < 128; ++c)
            s = fmaf(sq[r][c], W2[c * 24 + jj], s);
        long grow = row0 + r;
        if (jj & 1) bko[grow * NH + (jj >> 1)] = s;
        else        bqo[grow * NH + (jj >> 1)] = s;
    }

    for (int idx = tid; idx < 16 * 32; idx += 128) {
        int r = idx >> 5, p = idx & 31;
        long grow = row0 + r;
        int pos = (int)(grow & (SEQL - 1));
        float inv = __expf((float)p * -0.28782313662425576f); // 10000^(-p/32)
        float ang = (float)pos * inv;
        float sn, cs;
        __sincosf(ang, &sn, &cs);
        long base = grow * DD;
        float x0 = sq[r][2 * p], x1 = sq[r][2 * p + 1];
        qo[base + 2 * p]     = x0 * cs - x1 * sn;
        qo[base + 2 * p + 1] = x1 * cs + x0 * sn;
        float y0 = sq[r][DD + 2 * p], y1 = sq[r][DD + 2 * p + 1];
        ko[base + 2 * p]     = y0 * cs - y1 * sn;
        ko[base + 2 * p + 1] = y1 * cs + y0 * sn;
    }
}

// ---------------- Kernel 2: logits[b,h,m,n] = q.k/8 + bq[h,m] + bk[h,n] - tri - mask ----------------
// NEW STRUCTURE: 256 blocks (1/CU) x 512 threads. Block = (b, 32-row m-band), computes the full
// 32x1024 qk band in registers (k staged in 4 transposed 256-col chunks, kst reused), then stores
// h-outer with each WAVE emitting a fully LINEAR 16KB stream per head (block: contiguous 128KB/head).
// This matches fillBuffer's store pattern (the 6.9 TB/s reference) instead of 12-way 4MB-scatter.
__global__ __launch_bounds__(512, 2) void k2_logits(
    const float* __restrict__ q, const float* __restrict__ kmat,
    const float* __restrict__ bq, const float* __restrict__ bk,
    const int* __restrict__ mask, float* __restrict__ out)
{
    __shared__ float qs[32][64];     // 8 KB, wave-broadcast reads
    __shared__ float kst[64][256];   // 64 KB, transposed k chunk (reused 4x)
    __shared__ float bqs[32][12];    // 1.5 KB, broadcast reads
    __shared__ float bkst[12][1024]; // 48 KB, f4 wave-contiguous reads
    const int tid = threadIdx.x;
    const int lane = tid & 63;
    const int w = tid >> 6;          // wave 0..7, owns rows 4w..4w+3
    const int b = blockIdx.x >> 5;
    const int m0 = (blockIdx.x & 31) * 32;

    // q band: 32x64 = 512 f4 flat
    ((float4*)qs)[tid] = ((const float4*)(q + ((long)b * SEQL + m0) * DD))[tid];
    // bq band: 32x12 = 96 f4
    if (tid < 96)
        ((float4*)bqs)[tid] = ((const float4*)(bq + ((long)b * SEQL + m0) * NH))[tid];
    // bk all 1024 cols, transposed: rows n = tid, tid+512 (48B/row = 3 f4)
    #pragma unroll
    for (int base = 0; base < 1024; base += 512) {
        int n = base + tid;
        const float4* bsrc = (const float4*)(bk + ((long)b * SEQL + n) * NH);
        float4 v0 = bsrc[0], v1 = bsrc[1], v2 = bsrc[2];
        bkst[0][n] = v0.x; bkst[1][n]  = v0.y; bkst[2][n]  = v0.z; bkst[3][n]  = v0.w;
        bkst[4][n] = v1.x; bkst[5][n]  = v1.y; bkst[6][n]  = v1.z; bkst[7][n]  = v1.w;
        bkst[8][n] = v2.x; bkst[9][n]  = v2.y; bkst[10][n] = v2.z; bkst[11][n] = v2.w;
    }

    int mrow[4];
    #pragma unroll
    for (int r = 0; r < 4; ++r) mrow[r] = mask[b * SEQL + m0 + 4 * w + r];

    f32x4 acc[4][4];   // [row r][chunk c] -- all indexing compile-time (full unroll)
    #pragma unroll
    for (int r = 0; r < 4; ++r)
        #pragma unroll
        for (int c = 0; c < 4; ++c) acc[r][c] = 0.f;

    int mn[4][4];
    const int krow = tid >> 1;   // 0..255: local n within chunk
    const int khalf = tid & 1;   // which 32 k-dims

    #pragma unroll
    for (int c = 0; c < 4; ++c) {
        __syncthreads();  // protect kst reuse (first iter: also fences qs/bkst staging)
        const float4* ksrc = (const float4*)(kmat + ((long)b * SEQL + c * 256 + krow) * DD) + khalf * 8;
        #pragma unroll
        for (int t = 0; t < 8; ++t) {
            float4 kv = ksrc[t];
            int kd = khalf * 32 + t * 4;
            kst[kd + 0][krow] = kv.x; kst[kd + 1][krow] = kv.y;
            kst[kd + 2][krow] = kv.z; kst[kd + 3][krow] = kv.w;
        }
        __syncthreads();
        #pragma unroll
        for (int k4 = 0; k4 < 16; ++k4) {
            f32x4 kv0 = *(const f32x4*)&kst[4 * k4 + 0][4 * lane];
            f32x4 kv1 = *(const f32x4*)&kst[4 * k4 + 1][4 * lane];
            f32x4 kv2 = *(const f32x4*)&kst[4 * k4 + 2][4 * lane];
            f32x4 kv3 = *(const f32x4*)&kst[4 * k4 + 3][4 * lane];
            #pragma unroll
            for (int r = 0; r < 4; ++r) {
                const f32x4 qv = *(const f32x4*)&qs[4 * w + r][4 * k4];  // wave-broadcast
                acc[r][c] += qv.x * kv0;
                acc[r][c] += qv.y * kv1;
                acc[r][c] += qv.z * kv2;
                acc[r][c] += qv.w * kv3;
            }
        }
        const int4 m4 = *(const int4*)(mask + b * SEQL + c * 256 + 4 * lane);
        mn[c][0] = m4.x; mn[c][1] = m4.y; mn[c][2] = m4.z; mn[c][3] = m4.w;
    }

    // fold scale + causal tri + mask
    #pragma unroll
    for (int r = 0; r < 4; ++r) {
        const int m = m0 + 4 * w + r;
        #pragma unroll
        for (int c = 0; c < 4; ++c) {
            #pragma unroll
            for (int j = 0; j < 4; ++j) {
                const int n = c * 256 + 4 * lane + j;
                float v = acc[r][c][j] * 0.125f;
                if (m > n) v -= 1e12f;
                if (!(mrow[r] && mn[c][j])) v = -INFINITY;
                acc[r][c][j] = v;
            }
        }
    }

    // stores: h outer; per wave a fully LINEAR 16KB stream (r walks rows, c walks within-row)
    #pragma unroll 1
    for (int h = 0; h < NH; ++h) {
        f32x4 bkv[4];
        #pragma unroll
        for (int c = 0; c < 4; ++c)
            bkv[c] = *(const f32x4*)&bkst[h][c * 256 + 4 * lane];
        float* ob = out + ((long)(b * NH + h) << 20) + ((long)(m0 + 4 * w) << 10) + 4 * lane;
        #pragma unroll
        for (int r = 0; r < 4; ++r) {
            const float bqv = bqs[4 * w + r][h];
            #pragma unroll
            for (int c = 0; c < 4; ++c) {
                f32x4 v = acc[r][c] + bqv + bkv[c];
                __builtin_nontemporal_store(v, (f32x4*)(ob + ((long)r << 10) + c * 256));
            }
        }
    }
}

extern "C" void kernel_launch(void* const* d_in, const int* in_sizes, int n_in,
                              void* d_out, int out_size, void* d_ws, size_t ws_size,
                              hipStream_t stream) {
    const float* hidden = (const float*)d_in[0];
    const int*   mask   = (const int*)d_in[1];
    const float* W1     = (const float*)d_in[2];
    const float* b1     = (const float*)d_in[3];
    const float* W2     = (const float*)d_in[4];
    const float* b2     = (const float*)d_in[5];
    float* out = (float*)d_out;

    float* ws = (float*)d_ws;
    float* qbuf  = ws;                          // 8192*64
    float* kbuf  = qbuf + (long)NB * SEQL * DD; // 8192*64
    float* bqbuf = kbuf + (long)NB * SEQL * DD; // 8192*12
    float* bkbuf = bqbuf + (long)NB * SEQL * NH;

    k1_seq_rope_bias<<<512, 128, 0, stream>>>(hidden, W1, b1, W2, b2,
                                              qbuf, kbuf, bqbuf, bkbuf);
    k2_logits<<<256, 512, 0, stream>>>(qbuf, kbuf, bqbuf, bkbuf, mask, out);
}

// Round 8
// 905.779 us; speedup vs baseline: 1.0010x; 1.0010x over previous
//
#include <hip/hip_runtime.h>
#include <math.h>

#define HDIM 768
#define DD 64
#define SEQL 1024
#define NH 12
#define NB 8

typedef float f32x4 __attribute__((ext_vector_type(4)));

// ---------------- Kernel 1: seq = hidden@W1+b1, RoPE(q,k), bias = seq@W2+b2 ----------------
// 512 blocks x 128 threads; each block does 16 rows of the 8192-row problem. (unchanged)
__global__ __launch_bounds__(128) void k1_seq_rope_bias(
    const float* __restrict__ hidden, const float* __restrict__ W1,
    const float* __restrict__ b1, const float* __restrict__ W2,
    const float* __restrict__ b2,
    float* __restrict__ qo, float* __restrict__ ko,
    float* __restrict__ bqo, float* __restrict__ bko)
{
    __shared__ float hs[16 * HDIM];   // 48 KB: 16 hidden rows
    __shared__ float sq[16][132];     // seq tile (pad 132 for banks)
    const int tid = threadIdx.x;
    const long row0 = (long)blockIdx.x * 16;

    const float4* src = (const float4*)(hidden + row0 * HDIM);
    float4* hdst = (float4*)hs;
    #pragma unroll
    for (int t = 0; t < 24; ++t)
        hdst[tid + t * 128] = src[tid + t * 128];
    __syncthreads();

    const int cx = tid & 31;
    const int ry = tid >> 5;
    const float4 bias1 = ((const float4*)b1)[cx];
    float4 acc[4];
    #pragma unroll
    for (int r = 0; r < 4; ++r) acc[r] = bias1;

    for (int k4 = 0; k4 < HDIM / 4; ++k4) {
        float4 w[4];
        #pragma unroll
        for (int kk = 0; kk < 4; ++kk)
            w[kk] = *(const float4*)(W1 + (k4 * 4 + kk) * 128 + cx * 4);
        #pragma unroll
        for (int r = 0; r < 4; ++r) {
            float4 hv = *(const float4*)(hs + (ry * 4 + r) * HDIM + k4 * 4);
            acc[r].x = fmaf(hv.x, w[0].x, fmaf(hv.y, w[1].x, fmaf(hv.z, w[2].x, fmaf(hv.w, w[3].x, acc[r].x))));
            acc[r].y = fmaf(hv.x, w[0].y, fmaf(hv.y, w[1].y, fmaf(hv.z, w[2].y, fmaf(hv.w, w[3].y, acc[r].y))));
            acc[r].z = fmaf(hv.x, w[0].z, fmaf(hv.y, w[1].z, fmaf(hv.z, w[2].z, fmaf(hv.w, w[3].z, acc[r].z))));
            acc[r].w = fmaf(hv.x, w[0].w, fmaf(hv.y, w[1].w, fmaf(hv.z, w[2].w, fmaf(hv.w, w[3].w, acc[r].w))));
        }
    }
    #pragma unroll
    for (int r = 0; r < 4; ++r)
        *(float4*)&sq[ry * 4 + r][cx * 4] = acc[r];
    __syncthreads();

    for (int idx = tid; idx < 16 * 24; idx += 128) {
        int r = idx / 24, jj = idx - r * 24;
        float s = b2[jj];
        #pragma unroll 16
        for (int c = 0; c < 128; ++c)
            s = fmaf(sq[r][c], W2[c * 24 + jj], s);
        long grow = row0 + r;
        if (jj & 1) bko[grow * NH + (jj >> 1)] = s;
        else        bqo[grow * NH + (jj >> 1)] = s;
    }

    for (int idx = tid; idx < 16 * 32; idx += 128) {
        int r = idx >> 5, p = idx & 31;
        long grow = row0 + r;
        int pos = (int)(grow & (SEQL - 1));
        float inv = __expf((float)p * -0.28782313662425576f); // 10000^(-p/32)
        float ang = (float)pos * inv;
        float sn, cs;
        __sincosf(ang, &sn, &cs);
        long base = grow * DD;
        float x0 = sq[r][2 * p], x1 = sq[r][2 * p + 1];
        qo[base + 2 * p]     = x0 * cs - x1 * sn;
        qo[base + 2 * p + 1] = x1 * cs + x0 * sn;
        float y0 = sq[r][DD + 2 * p], y1 = sq[r][DD + 2 * p + 1];
        ko[base + 2 * p]     = y0 * cs - y1 * sn;
        ko[base + 2 * p + 1] = y1 * cs + y0 * sn;
    }
}

// ---------------- Kernel 2: logits[b,h,m,n] = q.k/8 + bq[h,m] + bk[h,n] - tri - mask ----------------
// 256 blocks (1/CU) x 512 threads. Block = (b, 32-row m-band), computes the full 32x1024 qk band in
// registers (k staged in 4 transposed 256-col chunks, kst reused), then stores h-outer with each WAVE
// emitting a fully LINEAR 16KB stream per head (block: contiguous 128KB/head).
// R7 bug fixed: __launch_bounds__(512) [no min-waves] -> VGPR cap 256, no scratch spills.
__global__ __launch_bounds__(512) void k2_logits(
    const float* __restrict__ q, const float* __restrict__ kmat,
    const float* __restrict__ bq, const float* __restrict__ bk,
    const int* __restrict__ mask, float* __restrict__ out)
{
    __shared__ float qs[32][64];     // 8 KB, wave-broadcast reads
    __shared__ float kst[64][256];   // 64 KB, transposed k chunk (reused 4x)
    __shared__ float bqs[32][12];    // 1.5 KB, broadcast reads
    __shared__ float bkst[12][1024]; // 48 KB, f4 wave-contiguous reads
    const int tid = threadIdx.x;
    const int lane = tid & 63;
    const int w = tid >> 6;          // wave 0..7, owns rows 4w..4w+3
    const int b = blockIdx.x >> 5;
    const int m0 = (blockIdx.x & 31) * 32;

    // q band: 32x64 = 512 f4 flat
    ((float4*)qs)[tid] = ((const float4*)(q + ((long)b * SEQL + m0) * DD))[tid];
    // bq band: 32x12 = 96 f4
    if (tid < 96)
        ((float4*)bqs)[tid] = ((const float4*)(bq + ((long)b * SEQL + m0) * NH))[tid];
    // bk all 1024 cols, transposed: rows n = tid, tid+512 (48B/row = 3 f4)
    #pragma unroll
    for (int base = 0; base < 1024; base += 512) {
        int n = base + tid;
        const float4* bsrc = (const float4*)(bk + ((long)b * SEQL + n) * NH);
        float4 v0 = bsrc[0], v1 = bsrc[1], v2 = bsrc[2];
        bkst[0][n] = v0.x; bkst[1][n]  = v0.y; bkst[2][n]  = v0.z; bkst[3][n]  = v0.w;
        bkst[4][n] = v1.x; bkst[5][n]  = v1.y; bkst[6][n]  = v1.z; bkst[7][n]  = v1.w;
        bkst[8][n] = v2.x; bkst[9][n]  = v2.y; bkst[10][n] = v2.z; bkst[11][n] = v2.w;
    }

    int mrow[4];
    #pragma unroll
    for (int r = 0; r < 4; ++r) mrow[r] = mask[b * SEQL + m0 + 4 * w + r];

    f32x4 acc[4][4];   // [row r][chunk c] -- all indexing compile-time (full unroll)
    #pragma unroll
    for (int r = 0; r < 4; ++r)
        #pragma unroll
        for (int c = 0; c < 4; ++c) acc[r][c] = 0.f;

    int mn[4][4];
    const int krow = tid >> 1;   // 0..255: local n within chunk
    const int khalf = tid & 1;   // which 32 k-dims

    #pragma unroll
    for (int c = 0; c < 4; ++c) {
        __syncthreads();  // protect kst reuse (first iter: also fences qs/bkst staging)
        const float4* ksrc = (const float4*)(kmat + ((long)b * SEQL + c * 256 + krow) * DD) + khalf * 8;
        #pragma unroll
        for (int t = 0; t < 8; ++t) {
            float4 kv = ksrc[t];
            int kd = khalf * 32 + t * 4;
            kst[kd + 0][krow] = kv.x; kst[kd + 1][krow] = kv.y;
            kst[kd + 2][krow] = kv.z; kst[kd + 3][krow] = kv.w;
        }
        __syncthreads();
        #pragma unroll
        for (int k4 = 0; k4 < 16; ++k4) {
            f32x4 kv0 = *(const f32x4*)&kst[4 * k4 + 0][4 * lane];
            f32x4 kv1 = *(const f32x4*)&kst[4 * k4 + 1][4 * lane];
            f32x4 kv2 = *(const f32x4*)&kst[4 * k4 + 2][4 * lane];
            f32x4 kv3 = *(const f32x4*)&kst[4 * k4 + 3][4 * lane];
            #pragma unroll
            for (int r = 0; r < 4; ++r) {
                const f32x4 qv = *(const f32x4*)&qs[4 * w + r][4 * k4];  // wave-broadcast
                acc[r][c] += qv.x * kv0;
                acc[r][c] += qv.y * kv1;
                acc[r][c] += qv.z * kv2;
                acc[r][c] += qv.w * kv3;
            }
        }
        const int4 m4 = *(const int4*)(mask + b * SEQL + c * 256 + 4 * lane);
        mn[c][0] = m4.x; mn[c][1] = m4.y; mn[c][2] = m4.z; mn[c][3] = m4.w;
    }

    // fold scale + causal tri + mask
    #pragma unroll
    for (int r = 0; r < 4; ++r) {
        const int m = m0 + 4 * w + r;
        #pragma unroll
        for (int c = 0; c < 4; ++c) {
            #pragma unroll
            for (int j = 0; j < 4; ++j) {
                const int n = c * 256 + 4 * lane + j;
                float v = acc[r][c][j] * 0.125f;
                if (m > n) v -= 1e12f;
                if (!(mrow[r] && mn[c][j])) v = -INFINITY;
                acc[r][c][j] = v;
            }
        }
    }

    // stores: h outer; per wave a fully LINEAR 16KB stream (r walks rows, c walks within-row)
    #pragma unroll 1
    for (int h = 0; h < NH; ++h) {
        f32x4 bkv[4];
        #pragma unroll
        for (int c = 0; c < 4; ++c)
            bkv[c] = *(const f32x4*)&bkst[h][c * 256 + 4 * lane];
        float* ob = out + ((long)(b * NH + h) << 20) + ((long)(m0 + 4 * w) << 10) + 4 * lane;
        #pragma unroll
        for (int r = 0; r < 4; ++r) {
            const float bqv = bqs[4 * w + r][h];
            #pragma unroll
            for (int c = 0; c < 4; ++c) {
                f32x4 v = acc[r][c] + bqv + bkv[c];
                __builtin_nontemporal_store(v, (f32x4*)(ob + ((long)r << 10) + c * 256));
            }
        }
    }
}

extern "C" void kernel_launch(void* const* d_in, const int* in_sizes, int n_in,
                              void* d_out, int out_size, void* d_ws, size_t ws_size,
                              hipStream_t stream) {
    const float* hidden = (const float*)d_in[0];
    const int*   mask   = (const int*)d_in[1];
    const float* W1     = (const float*)d_in[2];
    const float* b1     = (const float*)d_in[3];
    const float* W2     = (const float*)d_in[4];
    const float* b2     = (const float*)d_in[5];
    float* out = (float*)d_out;

    float* ws = (float*)d_ws;
    float* qbuf  = ws;                          // 8192*64
    float* kbuf  = qbuf + (long)NB * SEQL * DD; // 8192*64
    float* bqbuf = kbuf + (long)NB * SEQL * DD; // 8192*12
    float* bkbuf = bqbuf + (long)NB * SEQL * NH;

    k1_seq_rope_bias<<<512, 128, 0, stream>>>(hidden, W1, b1, W2, b2,
                                              qbuf, kbuf, bqbuf, bkbuf);
    k2_logits<<<256, 512, 0, stream>>>(qbuf, kbuf, bqbuf, bkbuf, mask, out);
}

// Round 10
// 136.829 us; speedup vs baseline: 6.6264x; 6.6198x over previous
//
#include <hip/hip_runtime.h>
#include <math.h>

#define HDIM 768
#define DD 64
#define SEQL 1024
#define NH 12
#define NB 8

typedef float f32x4 __attribute__((ext_vector_type(4)));

// ---------------- Kernel 1: seq = hidden@W1+b1, RoPE(q,k), bias = seq@W2+b2 ----------------
// 512 blocks x 128 threads; each block does 16 rows of the 8192-row problem. (unchanged)
__global__ __launch_bounds__(128) void k1_seq_rope_bias(
    const float* __restrict__ hidden, const float* __restrict__ W1,
    const float* __restrict__ b1, const float* __restrict__ W2,
    const float* __restrict__ b2,
    float* __restrict__ qo, float* __restrict__ ko,
    float* __restrict__ bqo, float* __restrict__ bko)
{
    __shared__ float hs[16 * HDIM];   // 48 KB: 16 hidden rows
    __shared__ float sq[16][132];     // seq tile (pad 132 for banks)
    const int tid = threadIdx.x;
    const long row0 = (long)blockIdx.x * 16;

    const float4* src = (const float4*)(hidden + row0 * HDIM);
    float4* hdst = (float4*)hs;
    #pragma unroll
    for (int t = 0; t < 24; ++t)
        hdst[tid + t * 128] = src[tid + t * 128];
    __syncthreads();

    const int cx = tid & 31;
    const int ry = tid >> 5;
    const float4 bias1 = ((const float4*)b1)[cx];
    float4 acc[4];
    #pragma unroll
    for (int r = 0; r < 4; ++r) acc[r] = bias1;

    for (int k4 = 0; k4 < HDIM / 4; ++k4) {
        float4 w[4];
        #pragma unroll
        for (int kk = 0; kk < 4; ++kk)
            w[kk] = *(const float4*)(W1 + (k4 * 4 + kk) * 128 + cx * 4);
        #pragma unroll
        for (int r = 0; r < 4; ++r) {
            float4 hv = *(const float4*)(hs + (ry * 4 + r) * HDIM + k4 * 4);
            acc[r].x = fmaf(hv.x, w[0].x, fmaf(hv.y, w[1].x, fmaf(hv.z, w[2].x, fmaf(hv.w, w[3].x, acc[r].x))));
            acc[r].y = fmaf(hv.x, w[0].y, fmaf(hv.y, w[1].y, fmaf(hv.z, w[2].y, fmaf(hv.w, w[3].y, acc[r].y))));
            acc[r].z = fmaf(hv.x, w[0].z, fmaf(hv.y, w[1].z, fmaf(hv.z, w[2].z, fmaf(hv.w, w[3].z, acc[r].z))));
            acc[r].w = fmaf(hv.x, w[0].w, fmaf(hv.y, w[1].w, fmaf(hv.z, w[2].w, fmaf(hv.w, w[3].w, acc[r].w))));
        }
    }
    #pragma unroll
    for (int r = 0; r < 4; ++r)
        *(float4*)&sq[ry * 4 + r][cx * 4] = acc[r];
    __syncthreads();

    for (int idx = tid; idx < 16 * 24; idx += 128) {
        int r = idx / 24, jj = idx - r * 24;
        float s = b2[jj];
        #pragma unroll 16
        for (int c = 0; c < 128; ++c)
            s = fmaf(sq[r][c], W2[c * 24 + jj], s);
        long grow = row0 + r;
        if (jj & 1) bko[grow * NH + (jj >> 1)] = s;
        else        bqo[grow * NH + (jj >> 1)] = s;
    }

    for (int idx = tid; idx < 16 * 32; idx += 128) {
        int r = idx >> 5, p = idx & 31;
        long grow = row0 + r;
        int pos = (int)(grow & (SEQL - 1));
        float inv = __expf((float)p * -0.28782313662425576f); // 10000^(-p/32)
        float ang = (float)pos * inv;
        float sn, cs;
        __sincosf(ang, &sn, &cs);
        long base = grow * DD;
        float x0 = sq[r][2 * p], x1 = sq[r][2 * p + 1];
        qo[base + 2 * p]     = x0 * cs - x1 * sn;
        qo[base + 2 * p + 1] = x1 * cs + x0 * sn;
        float y0 = sq[r][DD + 2 * p], y1 = sq[r][DD + 2 * p + 1];
        ko[base + 2 * p]     = y0 * cs - y1 * sn;
        ko[base + 2 * p + 1] = y1 * cs + y0 * sn;
    }
}

// ---------------- Kernel 2: logits[b,h,m,n] = q.k/8 + bq[h,m] + bk[h,n] - tri - mask ----------------
// R5 geometry: grid (4 n-tiles, 32 m-tiles, 8 b) x 256 threads, tile 32(m) x 256(n), NT 1KB-burst
// stores. CHANGE vs R5: compute+store split into 4 ROW-PAIR PASSES per wave -- after each pair's
// qk+fold, its 24 NT stores issue immediately and drain under the next pass's ds_read+FMA work.
// R9 bug fixed: store base uses nb (= n0 + 4*lane), not 4*lane.
__global__ __launch_bounds__(256) void k2_logits(
    const float* __restrict__ q, const float* __restrict__ kmat,
    const float* __restrict__ bq, const float* __restrict__ bk,
    const int* __restrict__ mask, float* __restrict__ out)
{
    __shared__ float qs[32][64];    // 8 KB, wave-broadcast reads
    __shared__ float kst[64][256];  // 64 KB, transposed k tile
    __shared__ float bqs[32][12];   // 1.5 KB, broadcast reads
    __shared__ float bkst[12][256]; // 12 KB, f4 wave-contiguous reads
    const int tid = threadIdx.x;
    const int lane = tid & 63;
    const int wv = tid >> 6;        // wave 0..3, owns rows 8*wv .. 8*wv+7
    const int b = blockIdx.z;
    const int m0 = blockIdx.y * 32;
    const int n0 = blockIdx.x * 256;

    // q tile: 32x64 row-major = flat copy, coalesced f4
    const float4* qsrc = (const float4*)(q + ((long)b * SEQL + m0) * DD);
    ((float4*)qs)[tid]       = qsrc[tid];
    ((float4*)qs)[tid + 256] = qsrc[tid + 256];

    // k tile transposed: thread walks its own row n=tid, scatter to kst[k][n]
    const float4* ksrc = (const float4*)(kmat + ((long)b * SEQL + n0 + tid) * DD);
    #pragma unroll
    for (int t = 0; t < 16; ++t) {
        float4 kv = ksrc[t];
        kst[t * 4 + 0][tid] = kv.x;
        kst[t * 4 + 1][tid] = kv.y;
        kst[t * 4 + 2][tid] = kv.z;
        kst[t * 4 + 3][tid] = kv.w;
    }

    // bq tile: 32x12 = 96 f4 flat
    if (tid < 96)
        ((float4*)bqs)[tid] = ((const float4*)(bq + ((long)b * SEQL + m0) * NH))[tid];

    // bk tile transposed: row n=tid, 12 floats = 3 f4
    {
        const float4* bsrc = (const float4*)(bk + ((long)b * SEQL + n0 + tid) * NH);
        float4 v0 = bsrc[0], v1 = bsrc[1], v2 = bsrc[2];
        bkst[0][tid] = v0.x; bkst[1][tid]  = v0.y; bkst[2][tid]  = v0.z; bkst[3][tid]  = v0.w;
        bkst[4][tid] = v1.x; bkst[5][tid]  = v1.y; bkst[6][tid]  = v1.z; bkst[7][tid]  = v1.w;
        bkst[8][tid] = v2.x; bkst[9][tid]  = v2.y; bkst[10][tid] = v2.z; bkst[11][tid] = v2.w;
    }
    __syncthreads();

    const int nb = n0 + 4 * lane;
    const int4 mn4 = *(const int4*)(mask + b * SEQL + nb);
    const int mn[4] = {mn4.x, mn4.y, mn4.z, mn4.w};

    // 4 row-pair passes: compute 2 rows' qk -> fold -> issue their 24 NT stores -> next pass
    #pragma unroll 1
    for (int p = 0; p < 4; ++p) {
        const int rp = wv * 8 + 2 * p;      // local rows rp, rp+1
        const int m = m0 + rp;

        f32x4 a0 = 0.f, a1 = 0.f;
        #pragma unroll
        for (int k4 = 0; k4 < 16; ++k4) {
            f32x4 kv0 = *(const f32x4*)&kst[4 * k4 + 0][4 * lane];
            f32x4 kv1 = *(const f32x4*)&kst[4 * k4 + 1][4 * lane];
            f32x4 kv2 = *(const f32x4*)&kst[4 * k4 + 2][4 * lane];
            f32x4 kv3 = *(const f32x4*)&kst[4 * k4 + 3][4 * lane];
            const f32x4 qv0 = *(const f32x4*)&qs[rp][4 * k4];       // wave-broadcast
            const f32x4 qv1 = *(const f32x4*)&qs[rp + 1][4 * k4];
            a0 += qv0.x * kv0; a0 += qv0.y * kv1; a0 += qv0.z * kv2; a0 += qv0.w * kv3;
            a1 += qv1.x * kv0; a1 += qv1.y * kv1; a1 += qv1.z * kv2; a1 += qv1.w * kv3;
        }

        // fold scale + causal tri + mask
        const int mr0 = mask[b * SEQL + m];
        const int mr1 = mask[b * SEQL + m + 1];
        #pragma unroll
        for (int j = 0; j < 4; ++j) {
            const int n = nb + j;
            float v0 = a0[j] * 0.125f;
            float v1 = a1[j] * 0.125f;
            if (m > n)     v0 -= 1e12f;
            if (m + 1 > n) v1 -= 1e12f;
            if (!(mr0 && mn[j])) v0 = -INFINITY;
            if (!(mr1 && mn[j])) v1 = -INFINITY;
            a0[j] = v0; a1[j] = v1;
        }

        // stores for this row pair, all 12 heads (drain under next pass's compute)
        #pragma unroll 1
        for (int h = 0; h < NH; ++h) {
            const f32x4 bkv = *(const f32x4*)&bkst[h][4 * lane];
            float* ob = out + ((long)(b * NH + h) << 20) + ((long)(m0 + rp) << 10) + nb;
            __builtin_nontemporal_store(a0 + bqs[rp][h] + bkv,     (f32x4*)ob);
            __builtin_nontemporal_store(a1 + bqs[rp + 1][h] + bkv, (f32x4*)(ob + SEQL));
        }
    }
}

extern "C" void kernel_launch(void* const* d_in, const int* in_sizes, int n_in,
                              void* d_out, int out_size, void* d_ws, size_t ws_size,
                              hipStream_t stream) {
    const float* hidden = (const float*)d_in[0];
    const int*   mask   = (const int*)d_in[1];
    const float* W1     = (const float*)d_in[2];
    const float* b1     = (const float*)d_in[3];
    const float* W2     = (const float*)d_in[4];
    const float* b2     = (const float*)d_in[5];
    float* out = (float*)d_out;

    float* ws = (float*)d_ws;
    float* qbuf  = ws;                          // 8192*64
    float* kbuf  = qbuf + (long)NB * SEQL * DD; // 8192*64
    float* bqbuf = kbuf + (long)NB * SEQL * DD; // 8192*12
    float* bkbuf = bqbuf + (long)NB * SEQL * NH;

    k1_seq_rope_bias<<<512, 128, 0, stream>>>(hidden, W1, b1, W2, b2,
                                              qbuf, kbuf, bqbuf, bkbuf);
    k2_logits<<<dim3(4, 32, 8), 256, 0, stream>>>(qbuf, kbuf, bqbuf, bkbuf, mask, out);
}